// Round 17
// baseline (136.686 us; speedup 1.0000x reference)
//
#include <hip/hip_runtime.h>
#include <stdint.h>

#define EMB 2048
#define NH 32
#define NKV 8
#define HD 64
#define SEQ 2048
#define QKV_N 3072   // 2048 q + 512 k + 512 v

using u16 = unsigned short;
typedef __attribute__((ext_vector_type(8))) short bf16x8;
typedef __attribute__((ext_vector_type(4))) float f32x4;
typedef __attribute__((ext_vector_type(4))) unsigned short u16x4;

#define MFMA16(a, b, c) __builtin_amdgcn_mfma_f32_16x16x32_bf16(a, b, c, 0, 0, 0)
#define EXP2_C8 11.5415603f   // 8 * log2(e); q pre-scaled by 0.125*log2(e)

__device__ inline u16 f2b(float f) {            // RNE
  union { float f; unsigned u; } v; v.f = f;
  unsigned r = v.u + 0x7fffu + ((v.u >> 16) & 1u);
  return (u16)(r >> 16);
}
__device__ inline u16 f2b_fast(float f) {       // round-half-up (attn P only)
  union { float f; unsigned u; } v; v.f = f;
  return (u16)((v.u + 0x8000u) >> 16);
}
__device__ inline float b2f(u16 u) {
  union { unsigned u; float f; } v; v.u = ((unsigned)u) << 16; return v.f;
}

__device__ inline void gload16(const void* g, void* l) {
  __builtin_amdgcn_global_load_lds(
      (const __attribute__((address_space(1))) void*)g,
      (__attribute__((address_space(3))) void*)l, 16, 0, 0);
}

// ------------- merged prep: x->bf16 convert + all weight transpose-converts -------------
__global__ void prep(const float* __restrict__ x, u16* __restrict__ xb,
                     const float* __restrict__ Wq, const float* __restrict__ Wk,
                     const float* __restrict__ Wv, const float* __restrict__ Wo,
                     u16* __restrict__ qkvT, u16* __restrict__ WoT) {
  int bx = blockIdx.x;
  if (bx >= 80) {                    // ---- x convert: 4096 units of 1024 floats ----
    int unit = (bx - 80) * 32 + blockIdx.y;
    int i = unit * 256 + threadIdx.x;
    float4 v = ((const float4*)x)[i];
    u16x4 o = { f2b(v.x), f2b(v.y), f2b(v.z), f2b(v.w) };
    ((u16x4*)xb)[i] = o;
    return;
  }
  __shared__ float t[64][65];
  int tx = threadIdx.x & 63, ty = threadIdx.x >> 6;
  int r0 = blockIdx.y * 64;
  const float* src; int C, c0, drow; u16* dst;
  if (bx < 32)      { src = Wq; C = 2048; c0 = bx * 64;        drow = bx * 64;        dst = qkvT; }
  else if (bx < 40) { src = Wk; C = 512;  c0 = (bx - 32) * 64; drow = bx * 64;        dst = qkvT; }
  else if (bx < 48) { src = Wv; C = 512;  c0 = (bx - 40) * 64; drow = bx * 64;        dst = qkvT; }
  else              { src = Wo; C = 2048; c0 = (bx - 48) * 64; drow = (bx - 48) * 64; dst = WoT; }
#pragma unroll
  for (int i = 0; i < 16; ++i) {
    int r = ty * 16 + i;
    t[r][tx] = src[(size_t)(r0 + r) * C + c0 + tx];
  }
  __syncthreads();
#pragma unroll
  for (int i = 0; i < 16; ++i) {
    int r = ty * 16 + i;
    dst[(size_t)(drow + r) * 2048 + r0 + tx] = f2b(t[tx][r]);
  }
}

// ---------------- bf16 GEMM, C = A @ B^T-layout; 64x128 tile for residency ------------
// OUT_MODE: 0 = f32 C, 2 = fused QKV epilogue (RMSNorm+RoPE q/k, transpose v)
template<int OUT_MODE>
__global__ __launch_bounds__(256, 2)
void gemm_bt(const u16* __restrict__ A, const u16* __restrict__ BT,
             float* __restrict__ Cp, int M, int N, int K, int nwgy,
             const float* __restrict__ cosT, const float* __restrict__ sinT,
             const float* __restrict__ qsc, const float* __restrict__ ksc,
             u16* __restrict__ qb, u16* __restrict__ kb, u16* __restrict__ vT) {
  __shared__ u16 As[2][64 * 64];    // 16 KB
  __shared__ u16 Bs[2][128 * 64];   // 32 KB
  const int tid = threadIdx.x;
  const int w = tid >> 6, lane = tid & 63;
  const int lr = lane & 15, lg = lane >> 4;
  const int nwg = gridDim.x, cpx = nwg >> 3, pos = blockIdx.x;
  const int o = (pos & 7) * cpx + (pos >> 3);      // bijective (nwg%8==0)
  const int by = o % nwgy, bx = o / nwgy;
  const int m0 = by * 64, n0 = bx * 128;
  const int wm = (w >> 1) * 32, wn = (w & 1) * 64;
  f32x4 acc[2][4] = {};
  const int nk = K >> 6;

  // LDS(row, chunk j) holds global chunk j^(row&7)  (16B chunks)
  auto STAGE = [&](int buf, int kt) {
    const int k0 = kt << 6;
    const int j = tid & 7;
    const int rr = tid >> 3;
#pragma unroll
    for (int i = 0; i < 2; ++i) {
      int r = i * 32 + rr;
      int sc = (j ^ (r & 7)) * 8;
      gload16(&A[(size_t)(m0 + r) * K + k0 + sc], (char*)As[buf] + i * 4096 + w * 1024);
    }
#pragma unroll
    for (int i = 0; i < 4; ++i) {
      int r = i * 32 + rr;
      int sc = (j ^ (r & 7)) * 8;
      gload16(&BT[(size_t)(n0 + r) * K + k0 + sc], (char*)Bs[buf] + i * 4096 + w * 1024);
    }
  };

  int cur = 0;
  STAGE(0, 0);
  asm volatile("s_waitcnt vmcnt(0)" ::: "memory");
  __syncthreads();
  for (int kt = 0; kt < nk; ++kt) {
    if (kt + 1 < nk) STAGE(cur ^ 1, kt + 1);
#pragma unroll
    for (int ks = 0; ks < 2; ++ks) {
      bf16x8 a[2], b[4];
#pragma unroll
      for (int i = 0; i < 2; ++i) {
        int row = wm + i * 16 + lr;
        a[i] = *(const bf16x8*)&As[cur][row * 64 + ((ks * 4 + lg) ^ (row & 7)) * 8];
      }
#pragma unroll
      for (int j = 0; j < 4; ++j) {
        int row = wn + j * 16 + lr;
        b[j] = *(const bf16x8*)&Bs[cur][row * 64 + ((ks * 4 + lg) ^ (row & 7)) * 8];
      }
#pragma unroll
      for (int i = 0; i < 2; ++i)
#pragma unroll
        for (int j = 0; j < 4; ++j)
          acc[i][j] = MFMA16(a[i], b[j], acc[i][j]);
    }
    asm volatile("s_waitcnt vmcnt(0)" ::: "memory");
    __syncthreads();
    cur ^= 1;
  }

  if (OUT_MODE == 0) {
#pragma unroll
    for (int i = 0; i < 2; ++i)
#pragma unroll
      for (int j = 0; j < 4; ++j)
#pragma unroll
        for (int r = 0; r < 4; ++r) {
          int row = m0 + wm + i * 16 + lg * 4 + r;
          int col = n0 + wn + j * 16 + lr;
          Cp[(size_t)row * N + col] = acc[i][j][r];
        }
  } else {
    // fused QKV epilogue. Wave tile = 32 rows x one full head (64 cols).
    const int hh = (n0 + wn) >> 6;   // 0..31 q, 32..39 k, 40..47 v
    if (hh < 40) {
      const float* scp = (hh < 32) ? qsc : ksc;
      u16* dst = (hh < 32) ? (qb + (size_t)hh * SEQ * HD)
                           : (kb + (size_t)(hh - 32) * SEQ * HD);
      // q gets 1/sqrt(64) * log2(e) folded in (exp2-based softmax downstream)
      const float qmul = (hh < 32) ? 0.18033688f : 1.0f;
#pragma unroll
      for (int i = 0; i < 2; ++i)
#pragma unroll
        for (int r = 0; r < 4; ++r) {
          float ssq = 0.f;
#pragma unroll
          for (int j = 0; j < 4; ++j) ssq += acc[i][j][r] * acc[i][j][r];
          ssq += __shfl_xor(ssq, 1);
          ssq += __shfl_xor(ssq, 2);
          ssq += __shfl_xor(ssq, 4);
          ssq += __shfl_xor(ssq, 8);
          float rs = rsqrtf(ssq * (1.0f / 64.0f) + 1e-6f);
          int s = m0 + wm + i * 16 + lg * 4 + r;
          float xn[4];
#pragma unroll
          for (int j = 0; j < 4; ++j) xn[j] = acc[i][j][r] * rs * scp[j * 16 + lr];
#pragma unroll
          for (int j = 0; j < 2; ++j) {
            int d = j * 16 + lr;
            float o1 = (xn[j] * cosT[s * 64 + d] - xn[j + 2] * sinT[s * 64 + d]) * qmul;
            float o2 = (xn[j + 2] * cosT[s * 64 + 32 + d] + xn[j] * sinT[s * 64 + 32 + d]) * qmul;
            dst[(size_t)s * 64 + d] = f2b(o1);
            dst[(size_t)s * 64 + 32 + d] = f2b(o2);
          }
        }
    } else {
      const int kvh = hh - 40;
      const int sbase = m0 + wm + lg * 4;
#pragma unroll
      for (int i = 0; i < 2; ++i)
#pragma unroll
        for (int j = 0; j < 4; ++j) {
          int d = j * 16 + lr;
          u16x4 pk = { f2b(acc[i][j][0]), f2b(acc[i][j][1]),
                       f2b(acc[i][j][2]), f2b(acc[i][j][3]) };
          *(u16x4*)&vT[((size_t)kvh * HD + d) * SEQ + sbase + i * 16] = pk;
        }
    }
  }
}

// ---------------- one 16(q) x 64(kv) attention tile step; STATIC max --------------------
// q pre-scaled by 0.125*log2e; softmax shift folded into MFMA C-init.
template<bool MASKED>
__device__ __forceinline__ void attn_step(
    const u16* __restrict__ Ks, const u16* __restrict__ VTs, u16* __restrict__ Psw,
    bf16x8 q0, bf16x8 q1, f32x4* O, float* l_acc,
    int qbase, int kbase, int lr, int lg) {
  f32x4 sc[4];
#pragma unroll
  for (int kj = 0; kj < 4; ++kj) {
    int r2 = kj * 16 + lr, sw = r2 & 7;
    bf16x8 kf0 = *(const bf16x8*)&Ks[r2 * 64 + (lg ^ sw) * 8];
    bf16x8 kf1 = *(const bf16x8*)&Ks[r2 * 64 + ((4 + lg) ^ sw) * 8];
    f32x4 z = { -EXP2_C8, -EXP2_C8, -EXP2_C8, -EXP2_C8 };
    z = MFMA16(q0, kf0, z);
    z = MFMA16(q1, kf1, z);
    sc[kj] = z;
  }
#pragma unroll
  for (int kj = 0; kj < 4; ++kj)
#pragma unroll
    for (int r = 0; r < 4; ++r) {
      float p;
      if (MASKED) {
        int qg = qbase + lg * 4 + r;
        int kg = kbase + kj * 16 + lr;
        p = (kg > qg) ? 0.0f : exp2f(sc[kj][r]);
      } else {
        p = exp2f(sc[kj][r]);
      }
      l_acc[r] += p;
      int row = lg * 4 + r, col = kj * 16 + lr;
      int sj = (col >> 3) ^ (row & 7);
      Psw[row * 64 + sj * 8 + (col & 7)] = f2b_fast(p);
    }
#pragma unroll
  for (int ks2 = 0; ks2 < 2; ++ks2) {
    bf16x8 pa = *(const bf16x8*)&Psw[lr * 64 + ((ks2 * 4 + lg) ^ (lr & 7)) * 8];
#pragma unroll
    for (int n = 0; n < 4; ++n) {
      int r3 = n * 16 + lr, sw3 = r3 & 7;
      bf16x8 vb = *(const bf16x8*)&VTs[r3 * 64 + ((ks2 * 4 + lg) ^ sw3) * 8];
      O[n] = MFMA16(pa, vb, O[n]);
    }
  }
}

// ---------------- causal GQA flash attention, SPLIT-K over KV range ---------------------
// Pair (p, 31-p) shares staged K/V as before, but the kt range is split between two
// blocks (s=0: [0,mid), s=1: [mid,qtB]) -> grid 1024, 4 blocks/CU (LDS 40KB exactly),
// total windows UNCHANGED (R7's confound removed). Static-max softmax makes the merge
// trivial: (O, l) partials just add. Partials: bf16 O in [col][row] layout (u16x4
// stores), f32 l. XCD chunk of 128 blocks = 4 heads = 1 kv-head (K/V L2-resident).
__global__ __launch_bounds__(256, 4)
void attn_sk(const u16* __restrict__ qb, const u16* __restrict__ kb,
             const u16* __restrict__ vT, u16* __restrict__ Opart,
             float* __restrict__ lpart) {
  __shared__ u16 Ks[2][64 * 64];    // 16 KB
  __shared__ u16 VTs[2][64 * 64];   // 16 KB
  __shared__ u16 Ps[4][16 * 64];    //  8 KB  -> 40 KB total
  const int tid = threadIdx.x, w = tid >> 6, lane = tid & 63;
  const int lr = lane & 15, lg = lane >> 4;
  const int pos = blockIdx.x;
  const int o = (pos & 7) * 128 + (pos >> 3);      // bijective for 1024
  const int h = o >> 5, p = (o >> 1) & 15, sh = o & 1;
  const int kvh = h >> 2;
  const int qtA = p, qtB = 31 - p;
  const int qbaseA = qtA * 64 + w * 16, qbaseB = qtB * 64 + w * 16;
  const int mid = (qtB + 2) >> 1;                  // ceil((qtB+1)/2)
  const int kt0 = sh ? mid : 0;
  const int kt1 = sh ? qtB : (mid - 1);
  u16* Psw = &Ps[w][0];

  bf16x8 qA0 = *(const bf16x8*)&qb[((size_t)h * SEQ + qbaseA + lr) * HD + lg * 8];
  bf16x8 qA1 = *(const bf16x8*)&qb[((size_t)h * SEQ + qbaseA + lr) * HD + 32 + lg * 8];
  bf16x8 qB0 = *(const bf16x8*)&qb[((size_t)h * SEQ + qbaseB + lr) * HD + lg * 8];
  bf16x8 qB1 = *(const bf16x8*)&qb[((size_t)h * SEQ + qbaseB + lr) * HD + 32 + lg * 8];

  f32x4 OA[4] = {}, OB[4] = {};
  float lA[4] = {0.f, 0.f, 0.f, 0.f}, lB[4] = {0.f, 0.f, 0.f, 0.f};

  auto STAGE = [&](int buf, int kt) {
    const int kbase = kt * 64;
#pragma unroll
    for (int i = 0; i < 2; ++i) {
      int c = i * 256 + tid;
      int r = c >> 3, j = c & 7, sj = j ^ (r & 7);
      gload16(&kb[((size_t)kvh * SEQ + kbase + r) * HD + sj * 8],
              (char*)Ks[buf] + i * 4096 + w * 1024);
      gload16(&vT[((size_t)kvh * HD + r) * SEQ + kbase + sj * 8],
              (char*)VTs[buf] + i * 4096 + w * 1024);
    }
  };

  STAGE(0, kt0);                     // 4 loads in flight
  int cur = 0;
  for (int kt = kt0; kt <= kt1; ++kt) {
    if (kt < kt1) {
      STAGE(cur ^ 1, kt + 1);        // +4 loads for next tile
      asm volatile("s_waitcnt vmcnt(4)" ::: "memory");
    } else {
      asm volatile("s_waitcnt vmcnt(0)" ::: "memory");
    }
    __builtin_amdgcn_s_barrier();    // loads for tile kt visible
    const int kbase = kt * 64;
    if (kt <= qtA) {
      if (kt == qtA)
        attn_step<true >(Ks[cur], VTs[cur], Psw, qA0, qA1, OA, lA, qbaseA, kbase, lr, lg);
      else
        attn_step<false>(Ks[cur], VTs[cur], Psw, qA0, qA1, OA, lA, qbaseA, kbase, lr, lg);
    }
    if (kt == qtB)
      attn_step<true >(Ks[cur], VTs[cur], Psw, qB0, qB1, OB, lB, qbaseB, kbase, lr, lg);
    else
      attn_step<false>(Ks[cur], VTs[cur], Psw, qB0, qB1, OB, lB, qbaseB, kbase, lr, lg);
    __builtin_amdgcn_s_barrier();    // all reads of buf[cur] done before overwrite
    cur ^= 1;
  }

  // reduce l over the 16 lr lanes (per q-row)
#pragma unroll
  for (int r = 0; r < 4; ++r) {
#pragma unroll
    for (int off = 1; off < 16; off <<= 1) {
      lA[r] += __shfl_xor(lA[r], off);
      lB[r] += __shfl_xor(lB[r], off);
    }
  }
  // write partials: O bf16 in [col 64][row 64] layout (lane's 4 rows are contiguous)
  const size_t baseA = ((size_t)(h * 32 + qtA) * 2 + sh) * 4096;
  const size_t baseB = ((size_t)(h * 32 + qtB) * 2 + sh) * 4096;
  const int rowb = w * 16 + lg * 4;
#pragma unroll
  for (int n = 0; n < 4; ++n) {
    int col = n * 16 + lr;
    u16x4 pa = { f2b(OA[n][0]), f2b(OA[n][1]), f2b(OA[n][2]), f2b(OA[n][3]) };
    *(u16x4*)&Opart[baseA + (size_t)col * 64 + rowb] = pa;
    u16x4 pb = { f2b(OB[n][0]), f2b(OB[n][1]), f2b(OB[n][2]), f2b(OB[n][3]) };
    *(u16x4*)&Opart[baseB + (size_t)col * 64 + rowb] = pb;
  }
  if (lr == 0) {
    const size_t lbA = ((size_t)(h * 32 + qtA) * 2 + sh) * 64;
    const size_t lbB = ((size_t)(h * 32 + qtB) * 2 + sh) * 64;
#pragma unroll
    for (int r = 0; r < 4; ++r) {
      lpart[lbA + rowb + r] = lA[r];
      lpart[lbB + rowb + r] = lB[r];
    }
  }
}

// ---------------- combine split-K partials -> ctxb bf16 (LDS transpose) -----------------
__global__ void combine(const u16* __restrict__ Opart, const float* __restrict__ lpart,
                        u16* __restrict__ ctxb) {
  __shared__ u16 tt[64][68];
  __shared__ float invl[64];
  const int h = blockIdx.x >> 5, qt = blockIdx.x & 31;
  const int t = threadIdx.x;
  const size_t b0 = ((size_t)(h * 32 + qt) * 2) * 4096;
  const size_t lb = ((size_t)(h * 32 + qt) * 2) * 64;
  if (t < 64) invl[t] = 1.0f / (lpart[lb + t] + lpart[lb + 64 + t]);
  __syncthreads();
#pragma unroll
  for (int it = 0; it < 16; ++it) {
    int e = it * 256 + t;            // linear over [col][row]
    int col = e >> 6, row = e & 63;
    float v = (b2f(Opart[b0 + e]) + b2f(Opart[b0 + 4096 + e])) * invl[row];
    tt[row][col] = f2b(v);
  }
  __syncthreads();
#pragma unroll
  for (int it = 0; it < 16; ++it) {
    int e = it * 256 + t;
    int row = e >> 6, col = e & 63;
    ctxb[(size_t)(qt * 64 + row) * 2048 + h * 64 + col] = tt[row][col];
  }
}

extern "C" void kernel_launch(void* const* d_in, const int* in_sizes, int n_in,
                              void* d_out, int out_size, void* d_ws, size_t ws_size,
                              hipStream_t stream) {
  const float* x    = (const float*)d_in[0];
  // d_in[1] = mask (causal triu, hardcoded in attn)
  const float* cosT = (const float*)d_in[2];
  const float* sinT = (const float*)d_in[3];
  const float* Wq   = (const float*)d_in[4];
  const float* Wk   = (const float*)d_in[5];
  const float* Wv   = (const float*)d_in[6];
  const float* Wo   = (const float*)d_in[7];
  const float* qsc  = (const float*)d_in[8];
  const float* ksc  = (const float*)d_in[9];
  float* out = (float*)d_out;

  char* wsp = (char*)d_ws;
  // [0,20) MB: xb (8) + WqkvT (12) -- dead after QKV GEMM; REUSED by attn partials:
  //   Opart bf16 [32h][32qt][2s][64col][64row] = 16 MiB at 0; lpart 512 KB at 16 MiB.
  u16*   xb    = (u16*)(wsp);                         //  8 MB [2048][2048]
  u16*   WqkvT = (u16*)(wsp + ((size_t)8  << 20));    // 12 MB [3072][2048]
  u16*   Opart = (u16*)(wsp);                         // 16 MiB (aliases xb+WqkvT)
  float* lpart = (float*)(wsp + ((size_t)16 << 20));  // 512 KB (aliases WqkvT tail)
  u16*   qbuf  = (u16*)(wsp + ((size_t)20 << 20));    //  8 MB [32][2048][64]
  u16*   kbuf  = (u16*)(wsp + ((size_t)28 << 20));    //  2 MB [8][2048][64]
  u16*   vTbuf = (u16*)(wsp + ((size_t)30 << 20));    //  2 MB [8][64][2048]
  u16*   WoT   = (u16*)(wsp + ((size_t)32 << 20));    //  8 MB [2048][2048]
  u16*   ctxb  = (u16*)(wsp + ((size_t)40 << 20));    //  8 MB [2048][2048]

  prep<<<dim3(208, 32), 256, 0, stream>>>(x, xb, Wq, Wk, Wv, Wo, WqkvT, WoT);

  gemm_bt<2><<<768, 256, 0, stream>>>(xb, WqkvT, nullptr, 2048, 3072, 2048, 32,
                                      cosT, sinT, qsc, ksc, qbuf, kbuf, vTbuf);
  attn_sk<<<1024, 256, 0, stream>>>(qbuf, kbuf, vTbuf, Opart, lpart);
  combine<<<1024, 256, 0, stream>>>(Opart, lpart, ctxb);
  gemm_bt<0><<<512, 256, 0, stream>>>((const u16*)ctxb, WoT, out, 2048, 2048, 2048, 32,
                                      nullptr, nullptr, nullptr, nullptr,
                                      nullptr, nullptr, nullptr);
}

// Round 18
// 124.758 us; speedup vs baseline: 1.0956x; 1.0956x over previous
//
#include <hip/hip_runtime.h>
#include <stdint.h>

#define EMB 2048
#define NH 32
#define NKV 8
#define HD 64
#define SEQ 2048
#define QKV_N 3072   // 2048 q + 512 k + 512 v

using u16 = unsigned short;
typedef __attribute__((ext_vector_type(8))) short bf16x8;
typedef __attribute__((ext_vector_type(4))) float f32x4;
typedef __attribute__((ext_vector_type(4))) unsigned short u16x4;

#define MFMA16(a, b, c) __builtin_amdgcn_mfma_f32_16x16x32_bf16(a, b, c, 0, 0, 0)
#define EXP2_C8 11.5415603f   // 8 * log2(e); q pre-scaled by 0.125*log2(e)

__device__ inline u16 f2b(float f) {            // RNE
  union { float f; unsigned u; } v; v.f = f;
  unsigned r = v.u + 0x7fffu + ((v.u >> 16) & 1u);
  return (u16)(r >> 16);
}
__device__ inline u16 f2b_fast(float f) {       // round-half-up (attn P only)
  union { float f; unsigned u; } v; v.f = f;
  return (u16)((v.u + 0x8000u) >> 16);
}

__device__ inline void gload16(const void* g, void* l) {
  __builtin_amdgcn_global_load_lds(
      (const __attribute__((address_space(1))) void*)g,
      (__attribute__((address_space(3))) void*)l, 16, 0, 0);
}

// ------------- merged prep: x->bf16 convert + all weight transpose-converts -------------
// bx < 80: weight transpose tiles (Wq|Wk|Wv -> qkvT rows, Wo -> WoT); bx >= 80: cvt units.
__global__ void prep(const float* __restrict__ x, u16* __restrict__ xb,
                     const float* __restrict__ Wq, const float* __restrict__ Wk,
                     const float* __restrict__ Wv, const float* __restrict__ Wo,
                     u16* __restrict__ qkvT, u16* __restrict__ WoT) {
  int bx = blockIdx.x;
  if (bx >= 80) {                    // ---- x convert: 4096 units of 1024 floats ----
    int unit = (bx - 80) * 32 + blockIdx.y;
    int i = unit * 256 + threadIdx.x;
    float4 v = ((const float4*)x)[i];
    u16x4 o = { f2b(v.x), f2b(v.y), f2b(v.z), f2b(v.w) };
    ((u16x4*)xb)[i] = o;
    return;
  }
  __shared__ float t[64][65];
  int tx = threadIdx.x & 63, ty = threadIdx.x >> 6;
  int r0 = blockIdx.y * 64;
  const float* src; int C, c0, drow; u16* dst;
  if (bx < 32)      { src = Wq; C = 2048; c0 = bx * 64;        drow = bx * 64;        dst = qkvT; }
  else if (bx < 40) { src = Wk; C = 512;  c0 = (bx - 32) * 64; drow = bx * 64;        dst = qkvT; }
  else if (bx < 48) { src = Wv; C = 512;  c0 = (bx - 40) * 64; drow = bx * 64;        dst = qkvT; }
  else              { src = Wo; C = 2048; c0 = (bx - 48) * 64; drow = (bx - 48) * 64; dst = WoT; }
#pragma unroll
  for (int i = 0; i < 16; ++i) {
    int r = ty * 16 + i;
    t[r][tx] = src[(size_t)(r0 + r) * C + c0 + tx];
  }
  __syncthreads();
#pragma unroll
  for (int i = 0; i < 16; ++i) {
    int r = ty * 16 + i;
    dst[(size_t)(drow + r) * 2048 + r0 + tx] = f2b(t[tx][r]);
  }
}

// ---------------- bf16 GEMM, C = A @ B^T-layout; 64x128 tile for residency ------------
// 2 waves-M x 2 waves-N; wave tile 32x64 (acc 2x4). LDS 48KB -> 3 blocks/CU.
// OUT_MODE: 0 = f32 C, 2 = fused QKV epilogue (RMSNorm+RoPE q/k, transpose v)
template<int OUT_MODE>
__global__ __launch_bounds__(256, 2)
void gemm_bt(const u16* __restrict__ A, const u16* __restrict__ BT,
             float* __restrict__ Cp, int M, int N, int K, int nwgy,
             const float* __restrict__ cosT, const float* __restrict__ sinT,
             const float* __restrict__ qsc, const float* __restrict__ ksc,
             u16* __restrict__ qb, u16* __restrict__ kb, u16* __restrict__ vT) {
  __shared__ u16 As[2][64 * 64];    // 16 KB
  __shared__ u16 Bs[2][128 * 64];   // 32 KB
  const int tid = threadIdx.x;
  const int w = tid >> 6, lane = tid & 63;
  const int lr = lane & 15, lg = lane >> 4;
  const int nwg = gridDim.x, cpx = nwg >> 3, pos = blockIdx.x;
  const int o = (pos & 7) * cpx + (pos >> 3);      // bijective (nwg%8==0)
  const int by = o % nwgy, bx = o / nwgy;
  const int m0 = by * 64, n0 = bx * 128;
  const int wm = (w >> 1) * 32, wn = (w & 1) * 64;
  f32x4 acc[2][4] = {};
  const int nk = K >> 6;

  // LDS(row, chunk j) holds global chunk j^(row&7)  (16B chunks)
  auto STAGE = [&](int buf, int kt) {
    const int k0 = kt << 6;
    const int j = tid & 7;
    const int rr = tid >> 3;
#pragma unroll
    for (int i = 0; i < 2; ++i) {
      int r = i * 32 + rr;
      int sc = (j ^ (r & 7)) * 8;
      gload16(&A[(size_t)(m0 + r) * K + k0 + sc], (char*)As[buf] + i * 4096 + w * 1024);
    }
#pragma unroll
    for (int i = 0; i < 4; ++i) {
      int r = i * 32 + rr;
      int sc = (j ^ (r & 7)) * 8;
      gload16(&BT[(size_t)(n0 + r) * K + k0 + sc], (char*)Bs[buf] + i * 4096 + w * 1024);
    }
  };

  int cur = 0;
  STAGE(0, 0);
  asm volatile("s_waitcnt vmcnt(0)" ::: "memory");
  __syncthreads();
  for (int kt = 0; kt < nk; ++kt) {
    if (kt + 1 < nk) STAGE(cur ^ 1, kt + 1);
#pragma unroll
    for (int ks = 0; ks < 2; ++ks) {
      bf16x8 a[2], b[4];
#pragma unroll
      for (int i = 0; i < 2; ++i) {
        int row = wm + i * 16 + lr;
        a[i] = *(const bf16x8*)&As[cur][row * 64 + ((ks * 4 + lg) ^ (row & 7)) * 8];
      }
#pragma unroll
      for (int j = 0; j < 4; ++j) {
        int row = wn + j * 16 + lr;
        b[j] = *(const bf16x8*)&Bs[cur][row * 64 + ((ks * 4 + lg) ^ (row & 7)) * 8];
      }
#pragma unroll
      for (int i = 0; i < 2; ++i)
#pragma unroll
        for (int j = 0; j < 4; ++j)
          acc[i][j] = MFMA16(a[i], b[j], acc[i][j]);
    }
    asm volatile("s_waitcnt vmcnt(0)" ::: "memory");
    __syncthreads();
    cur ^= 1;
  }

  if (OUT_MODE == 0) {
#pragma unroll
    for (int i = 0; i < 2; ++i)
#pragma unroll
      for (int j = 0; j < 4; ++j)
#pragma unroll
        for (int r = 0; r < 4; ++r) {
          int row = m0 + wm + i * 16 + lg * 4 + r;
          int col = n0 + wn + j * 16 + lr;
          Cp[(size_t)row * N + col] = acc[i][j][r];
        }
  } else {
    // fused QKV epilogue. Wave tile = 32 rows x one full head (64 cols).
    const int hh = (n0 + wn) >> 6;   // 0..31 q, 32..39 k, 40..47 v
    if (hh < 40) {
      const float* scp = (hh < 32) ? qsc : ksc;
      u16* dst = (hh < 32) ? (qb + (size_t)hh * SEQ * HD)
                           : (kb + (size_t)(hh - 32) * SEQ * HD);
      // q gets 1/sqrt(64) * log2(e) folded in (exp2-based softmax downstream)
      const float qmul = (hh < 32) ? 0.18033688f : 1.0f;
#pragma unroll
      for (int i = 0; i < 2; ++i)
#pragma unroll
        for (int r = 0; r < 4; ++r) {
          float ssq = 0.f;
#pragma unroll
          for (int j = 0; j < 4; ++j) ssq += acc[i][j][r] * acc[i][j][r];
          ssq += __shfl_xor(ssq, 1);
          ssq += __shfl_xor(ssq, 2);
          ssq += __shfl_xor(ssq, 4);
          ssq += __shfl_xor(ssq, 8);
          float rs = rsqrtf(ssq * (1.0f / 64.0f) + 1e-6f);
          int s = m0 + wm + i * 16 + lg * 4 + r;
          float xn[4];
#pragma unroll
          for (int j = 0; j < 4; ++j) xn[j] = acc[i][j][r] * rs * scp[j * 16 + lr];
#pragma unroll
          for (int j = 0; j < 2; ++j) {
            int d = j * 16 + lr;
            float o1 = (xn[j] * cosT[s * 64 + d] - xn[j + 2] * sinT[s * 64 + d]) * qmul;
            float o2 = (xn[j + 2] * cosT[s * 64 + 32 + d] + xn[j] * sinT[s * 64 + 32 + d]) * qmul;
            dst[(size_t)s * 64 + d] = f2b(o1);
            dst[(size_t)s * 64 + 32 + d] = f2b(o2);
          }
        }
    } else {
      const int kvh = hh - 40;
      const int sbase = m0 + wm + lg * 4;
#pragma unroll
      for (int i = 0; i < 2; ++i)
#pragma unroll
        for (int j = 0; j < 4; ++j) {
          int d = j * 16 + lr;
          u16x4 pk = { f2b(acc[i][j][0]), f2b(acc[i][j][1]),
                       f2b(acc[i][j][2]), f2b(acc[i][j][3]) };
          *(u16x4*)&vT[((size_t)kvh * HD + d) * SEQ + sbase + i * 16] = pk;
        }
    }
  }
}

// ---------------- one 16(q) x 64(kv) attention tile step; STATIC max --------------------
// q pre-scaled by 0.125*log2e; the softmax shift (-8*log2e) is folded into the MFMA
// accumulator init, so P = exp2(sc) directly. Exact softmax by shift invariance
// (|q.k/8| <= 8 via Cauchy-Schwarz on rmsnormed q,k).
template<bool MASKED>
__device__ __forceinline__ void attn_step(
    const u16* __restrict__ Ks, const u16* __restrict__ VTs, u16* __restrict__ Psw,
    bf16x8 q0, bf16x8 q1, f32x4* O, float* l_acc,
    int qbase, int kbase, int lr, int lg) {
  f32x4 sc[4];
#pragma unroll
  for (int kj = 0; kj < 4; ++kj) {
    int r2 = kj * 16 + lr, sw = r2 & 7;
    bf16x8 kf0 = *(const bf16x8*)&Ks[r2 * 64 + (lg ^ sw) * 8];
    bf16x8 kf1 = *(const bf16x8*)&Ks[r2 * 64 + ((4 + lg) ^ sw) * 8];
    f32x4 z = { -EXP2_C8, -EXP2_C8, -EXP2_C8, -EXP2_C8 };  // shift folded into C-init
    z = MFMA16(q0, kf0, z);
    z = MFMA16(q1, kf1, z);
    sc[kj] = z;
  }
#pragma unroll
  for (int kj = 0; kj < 4; ++kj)
#pragma unroll
    for (int r = 0; r < 4; ++r) {
      float p;
      if (MASKED) {
        int qg = qbase + lg * 4 + r;
        int kg = kbase + kj * 16 + lr;
        p = (kg > qg) ? 0.0f : exp2f(sc[kj][r]);
      } else {
        p = exp2f(sc[kj][r]);
      }
      l_acc[r] += p;
      int row = lg * 4 + r, col = kj * 16 + lr;
      int sj = (col >> 3) ^ (row & 7);
      Psw[row * 64 + sj * 8 + (col & 7)] = f2b_fast(p);
    }
  // PV: P(16x64) @ V-tiles
#pragma unroll
  for (int ks2 = 0; ks2 < 2; ++ks2) {
    bf16x8 pa = *(const bf16x8*)&Psw[lr * 64 + ((ks2 * 4 + lg) ^ (lr & 7)) * 8];
#pragma unroll
    for (int n = 0; n < 4; ++n) {
      int r3 = n * 16 + lr, sw3 = r3 & 7;
      bf16x8 vb = *(const bf16x8*)&VTs[r3 * 64 + ((ks2 * 4 + lg) ^ sw3) * 8];
      O[n] = MFMA16(pa, vb, O[n]);
    }
  }
}

// ---------------- causal GQA flash attention, paired q-tiles, depth-3 ring --------------
// R6 mapping (empirical best across 8 tried variants). Depth-3 LDS ring -> ONE barrier
// per window; vmcnt(4) completes exactly tile-kt's loads while next tile stays in flight.
__global__ __launch_bounds__(256, 2)
void attn(const u16* __restrict__ qb, const u16* __restrict__ kb,
          const u16* __restrict__ vT, u16* __restrict__ ctx) {
  __shared__ u16 Ks[3][64 * 64];    // 24 KB
  __shared__ u16 VTs[3][64 * 64];   // 24 KB
  __shared__ u16 Ps[4][16 * 64];    //  8 KB
  const int tid = threadIdx.x, w = tid >> 6, lane = tid & 63;
  const int lr = lane & 15, lg = lane >> 4;
  const int pos = blockIdx.x;
  const int o = (pos & 7) * 64 + (pos >> 3);       // bijective for 512
  const int h = o >> 4, p = o & 15;
  const int kvh = h >> 2;
  const int qtA = p, qtB = 31 - p;
  const int qbaseA = qtA * 64 + w * 16, qbaseB = qtB * 64 + w * 16;
  u16* Psw = &Ps[w][0];

  bf16x8 qA0 = *(const bf16x8*)&qb[((size_t)h * SEQ + qbaseA + lr) * HD + lg * 8];
  bf16x8 qA1 = *(const bf16x8*)&qb[((size_t)h * SEQ + qbaseA + lr) * HD + 32 + lg * 8];
  bf16x8 qB0 = *(const bf16x8*)&qb[((size_t)h * SEQ + qbaseB + lr) * HD + lg * 8];
  bf16x8 qB1 = *(const bf16x8*)&qb[((size_t)h * SEQ + qbaseB + lr) * HD + 32 + lg * 8];

  f32x4 OA[4] = {}, OB[4] = {};
  float lA[4] = {0.f, 0.f, 0.f, 0.f}, lB[4] = {0.f, 0.f, 0.f, 0.f};

  auto STAGE = [&](int buf, int kt) {
    const int kbase = kt * 64;
#pragma unroll
    for (int i = 0; i < 2; ++i) {
      int c = i * 256 + tid;
      int r = c >> 3, j = c & 7, sj = j ^ (r & 7);
      gload16(&kb[((size_t)kvh * SEQ + kbase + r) * HD + sj * 8],
              (char*)Ks[buf] + i * 4096 + w * 1024);
      gload16(&vT[((size_t)kvh * HD + r) * SEQ + kbase + sj * 8],
              (char*)VTs[buf] + i * 4096 + w * 1024);
    }
  };

  STAGE(0, 0);                       // 4 loads in flight
  int cur = 0, nxt = 1;
  for (int kt = 0; kt <= qtB; ++kt) {
    if (kt < qtB) {
      STAGE(nxt, kt + 1);            // +4 loads; overwrite target is 2 windows stale
      asm volatile("s_waitcnt vmcnt(4)" ::: "memory");  // tile-kt loads complete
    } else {
      asm volatile("s_waitcnt vmcnt(0)" ::: "memory");
    }
    __builtin_amdgcn_s_barrier();    // single barrier per window
    const int kbase = kt * 64;
    if (kt <= qtA) {
      if (kt == qtA)
        attn_step<true >(Ks[cur], VTs[cur], Psw, qA0, qA1, OA, lA, qbaseA, kbase, lr, lg);
      else
        attn_step<false>(Ks[cur], VTs[cur], Psw, qA0, qA1, OA, lA, qbaseA, kbase, lr, lg);
    }
    if (kt == qtB)
      attn_step<true >(Ks[cur], VTs[cur], Psw, qB0, qB1, OB, lB, qbaseB, kbase, lr, lg);
    else
      attn_step<false>(Ks[cur], VTs[cur], Psw, qB0, qB1, OB, lB, qbaseB, kbase, lr, lg);
    cur = nxt;
    nxt = (nxt == 2) ? 0 : nxt + 1;
  }

#pragma unroll
  for (int r = 0; r < 4; ++r) {
#pragma unroll
    for (int off = 1; off < 16; off <<= 1) {
      lA[r] += __shfl_xor(lA[r], off);
      lB[r] += __shfl_xor(lB[r], off);
    }
  }
#pragma unroll
  for (int n = 0; n < 4; ++n)
#pragma unroll
    for (int r = 0; r < 4; ++r) {
      int sA = qbaseA + lg * 4 + r;
      ctx[(size_t)sA * 2048 + h * 64 + n * 16 + lr] = f2b(OA[n][r] / lA[r]);
      int sB = qbaseB + lg * 4 + r;
      ctx[(size_t)sB * 2048 + h * 64 + n * 16 + lr] = f2b(OB[n][r] / lB[r]);
    }
}

extern "C" void kernel_launch(void* const* d_in, const int* in_sizes, int n_in,
                              void* d_out, int out_size, void* d_ws, size_t ws_size,
                              hipStream_t stream) {
  const float* x    = (const float*)d_in[0];
  // d_in[1] = mask (causal triu, hardcoded in attn)
  const float* cosT = (const float*)d_in[2];
  const float* sinT = (const float*)d_in[3];
  const float* Wq   = (const float*)d_in[4];
  const float* Wk   = (const float*)d_in[5];
  const float* Wv   = (const float*)d_in[6];
  const float* Wo   = (const float*)d_in[7];
  const float* qsc  = (const float*)d_in[8];
  const float* ksc  = (const float*)d_in[9];
  float* out = (float*)d_out;

  char* wsp = (char*)d_ws;
  u16*   xb    = (u16*)(wsp);                         //  8 MB [2048][2048]
  u16*   WqkvT = (u16*)(wsp + ((size_t)8  << 20));    // 12 MB [3072][2048]
  u16*   WoT   = (u16*)(wsp + ((size_t)20 << 20));    //  8 MB [2048][2048]
  u16*   qbuf  = (u16*)(wsp + ((size_t)28 << 20));    //  8 MB [32][2048][64]
  u16*   kbuf  = (u16*)(wsp + ((size_t)36 << 20));    //  2 MB [8][2048][64]
  u16*   vTbuf = (u16*)(wsp + ((size_t)38 << 20));    //  2 MB [8][64][2048]
  u16*   ctxb  = (u16*)(wsp + ((size_t)40 << 20));    //  8 MB [2048][2048]

  prep<<<dim3(208, 32), 256, 0, stream>>>(x, xb, Wq, Wk, Wv, Wo, WqkvT, WoT);

  gemm_bt<2><<<768, 256, 0, stream>>>(xb, WqkvT, nullptr, 2048, 3072, 2048, 32,
                                      cosT, sinT, qsc, ksc, qbuf, kbuf, vTbuf);
  attn<<<512, 256, 0, stream>>>(qbuf, kbuf, vTbuf, ctxb);
  gemm_bt<0><<<512, 256, 0, stream>>>((const u16*)ctxb, WoT, out, 2048, 2048, 2048, 32,
                                      nullptr, nullptr, nullptr, nullptr,
                                      nullptr, nullptr, nullptr);
}